// Round 1
// baseline (233.283 us; speedup 1.0000x reference)
//
#include <hip/hip_runtime.h>
#include <float.h>

#define BB 2
#define CC 32
#define HH 96
#define WW 128
#define WP 129               // padded LDS row stride (bank-conflict-free row/col sums)
#define HW (HH*WW)           // 12288
#define BC (BB*CC)           // 64
#define NPLANE (BC*HW)       // 786432
#define EPSF 1e-6f

// ---- workspace layout (float offsets) ----
#define QR_OFF 0                               // [B*C][H] query row sums
#define QC_OFF (QR_OFF + BC*HH)                // [B*C][W] query col sums
#define QS_OFF (QC_OFF + BC*WW)                // [B*C]    query totals
#define KR_OFF (QS_OFF + BC)                   // [B*C][H] key row sums
#define KC_OFF (KR_OFF + BC*HH)                // [B*C][W] key col sums
#define KS_OFF (KC_OFF + BC*WW)                // [B*C]    key totals
#define HR_OFF (KS_OFF + BC)                   // [C0][B*C][H] h_row (normed)
#define HC_OFF (HR_OFF + CC*BC*HH)             // [C0][B*C][H] h_col
#define WR_OFF (HC_OFF + CC*BC*HH)             // [C0][B*C][W] w_row
#define WC_OFF (WR_OFF + CC*BC*WW)             // [C0][B*C][W] w_col
#define RV_OFF (WC_OFF + CC*BC*WW)             // [C0][B*C][H][4] 1/R per term
#define CV_OFF (RV_OFF + CC*BC*HH*4)           // [C0][B*C][W][4] 1/C per term
#define MX_OFF (CV_OFF + CC*BC*WW*4)           // [C0][4] rcmax (atomicMax bits)
#define SMX_OFF (MX_OFF + CC*4)                // [C0]    smax
#define WS_FLOATS (SMX_OFF + CC)               // total = 2781472 floats (~11.2 MB)

// block-wide max, 256 threads = 4 waves of 64
__device__ __forceinline__ float blkmax4(float v) {
  __shared__ float sred[4];
  #pragma unroll
  for (int o = 32; o > 0; o >>= 1) v = fmaxf(v, __shfl_xor(v, o, 64));
  if ((threadIdx.x & 63) == 0) sred[threadIdx.x >> 6] = v;
  __syncthreads();
  float r = fmaxf(fmaxf(sred[0], sred[1]), fmaxf(sred[2], sred[3]));
  __syncthreads();
  return r;
}

// ---------------- K1: per-plane row/col/total sums (queries and keys) ----------------
__global__ __launch_bounds__(256) void k1_plane_sums(const float* __restrict__ q,
                                                     const float* __restrict__ k,
                                                     float* __restrict__ ws) {
  int pb = blockIdx.x;                 // [0, 2*BC): first BC = queries, rest = keys
  int plane = pb & (BC - 1);
  const float* src = (pb < BC ? q : k) + (size_t)plane * HW;
  float* rowO = ws + (pb < BC ? QR_OFF : KR_OFF) + plane * HH;
  float* colO = ws + (pb < BC ? QC_OFF : KC_OFF) + plane * WW;
  float* totO = ws + (pb < BC ? QS_OFF : KS_OFF) + plane;
  __shared__ float e[HH * WP];
  __shared__ float rs[HH];
  int tid = threadIdx.x;
  for (int i = tid; i < HW; i += 256) {
    int h = i >> 7, w = i & 127;
    e[h * WP + w] = src[i];
  }
  __syncthreads();
  if (tid < HH) {
    float s = 0.f;
    for (int w = 0; w < WW; ++w) s += e[tid * WP + w];
    rowO[tid] = s; rs[tid] = s;
  }
  if (tid < WW) {
    float s = 0.f;
    for (int h = 0; h < HH; ++h) s += e[h * WP + tid];
    colO[tid] = s;
  }
  __syncthreads();
  if (tid == 0) {
    float s = 0.f;
    for (int h = 0; h < HH; ++h) s += rs[h];
    *totO = s;
  }
}

// ---------------- K2: min-max-normalized vectors per (c0, type) ----------------
__device__ __forceinline__ float k2_raw(const float* __restrict__ ws, int type, int c0, int i, int L) {
  int bc = i / L, x = i - bc * L;
  int b = bc >> 5;                     // CC == 32
  if (type == 0) return ws[QS_OFF + b * CC + c0] * ws[KR_OFF + bc * HH + x] + HH * EPSF;
  if (type == 1) return ws[QR_OFF + (b * CC + c0) * HH + x] * ws[KS_OFF + bc] + HH * EPSF;
  if (type == 2) return ws[QS_OFF + b * CC + c0] * ws[KC_OFF + bc * WW + x] + WW * EPSF;
  return ws[QC_OFF + (b * CC + c0) * WW + x] * ws[KS_OFF + bc] + WW * EPSF;
}

__global__ __launch_bounds__(256) void k2_vec_norm(float* __restrict__ ws) {
  int c0 = blockIdx.x >> 2, type = blockIdx.x & 3;
  int L = (type < 2) ? HH : WW;
  int N = BC * L;
  int tid = threadIdx.x;
  float mx = -FLT_MAX, mn = FLT_MAX;
  for (int i = tid; i < N; i += 256) {
    float v = k2_raw(ws, type, c0, i, L);
    mx = fmaxf(mx, v); mn = fminf(mn, v);
  }
  mx = blkmax4(mx);
  mn = -blkmax4(-mn);
  float scale = 1.0f / (mx - mn);
  int dst = (type == 0 ? HR_OFF : type == 1 ? HC_OFF : type == 2 ? WR_OFF : WC_OFF) + c0 * N;
  for (int i = tid; i < N; i += 256) {
    float v = k2_raw(ws, type, c0, i, L);
    ws[dst + i] = 2.0f + (v - mn) * scale;
  }
}

// ---------------- K3: per (c0,b,c): 1/R,1/C per term + global rcmax ----------------
__global__ __launch_bounds__(256) void k3_rc(float* __restrict__ ws) {
  int gid = blockIdx.x;                // c0*BC + plane
  int c0 = gid >> 6;                   // BC == 64
  int tid = threadIdx.x;
  __shared__ float e[HH * WP];         // ~49.5 KB, padded
  __shared__ float mv[HH], nv[WW], rR[HH], rC[WW];
  int vb = gid;
  for (int t = 0; t < 4; ++t) {
    const float* msrc = ws + (t < 2 ? HR_OFF : HC_OFF) + vb * HH;
    const float* nsrc = ws + ((t & 1) == 0 ? WR_OFF : WC_OFF) + vb * WW;
    if (tid < HH) mv[tid] = msrc[tid];
    if (tid < WW) nv[tid] = nsrc[tid];
    __syncthreads();
    for (int i = tid; i < HW; i += 256) {
      int h = i >> 7, w = i & 127;
      e[h * WP + w] = __expf(mv[h] * nv[w]);
    }
    __syncthreads();
    if (tid < HH) {
      float s = 0.f;
      for (int w = 0; w < WW; ++w) s += e[tid * WP + w];
      float r = 1.0f / s;
      rR[tid] = r;
      ws[RV_OFF + (vb * HH + tid) * 4 + t] = r;
    }
    if (tid < WW) {
      float s = 0.f;
      for (int h = 0; h < HH; ++h) s += e[h * WP + tid];
      float r = 1.0f / s;
      rC[tid] = r;
      ws[CV_OFF + (vb * WW + tid) * 4 + t] = r;
    }
    __syncthreads();
    float lm = 0.f;
    for (int i = tid; i < HW; i += 256) {
      int h = i >> 7, w = i & 127;
      lm = fmaxf(lm, e[h * WP + w] * (rR[h] + rC[w]));
    }
    lm = blkmax4(lm);
    if (tid == 0)
      atomicMax(reinterpret_cast<unsigned int*>(ws + MX_OFF + c0 * 4 + t), __float_as_uint(lm));
    __syncthreads();
  }
}

// ---------------- K4: per (c0,b,tile): score, smax, unnormalized z ----------------
#define ELEMS 8
#define TILES 6                        // 256*ELEMS*TILES == HW
__global__ __launch_bounds__(256) void k4_score(const float* __restrict__ values,
                                                float* __restrict__ ws,
                                                float* __restrict__ out) {
  int bx = blockIdx.x;                 // (c0*BB + b)*TILES + tile
  int tile = bx % TILES;
  int cb = bx / TILES;
  int b = cb & 1, c0 = cb >> 1;
  int tid = threadIdx.x;
  int base = tile * (256 * ELEMS);
  __shared__ float2 mh2[HH];
  __shared__ float2 nw2[WW];
  __shared__ float4 R4[HH];
  __shared__ float4 C4[WW];
  float im[4];
  #pragma unroll
  for (int t = 0; t < 4; ++t) im[t] = 1.0f / ws[MX_OFF + c0 * 4 + t];
  float U[ELEMS];
  #pragma unroll
  for (int j = 0; j < ELEMS; ++j) U[j] = 0.f;
  int hh_[ELEMS], ww_[ELEMS];
  #pragma unroll
  for (int j = 0; j < ELEMS; ++j) { int idx = base + tid + 256 * j; hh_[j] = idx >> 7; ww_[j] = idx & 127; }
  float smaxl = 0.f;
  for (int c = 0; c < CC; ++c) {
    int plane = b * CC + c;
    int vb = c0 * BC + plane;
    __syncthreads();                   // protect LDS from previous iteration readers
    if (tid < HH) mh2[tid] = make_float2(ws[HR_OFF + vb * HH + tid], ws[HC_OFF + vb * HH + tid]);
    if (tid < WW) nw2[tid] = make_float2(ws[WR_OFF + vb * WW + tid], ws[WC_OFF + vb * WW + tid]);
    for (int i = tid; i < HH * 4; i += 256) reinterpret_cast<float*>(R4)[i] = ws[RV_OFF + vb * HH * 4 + i];
    for (int i = tid; i < WW * 4; i += 256) reinterpret_cast<float*>(C4)[i] = ws[CV_OFF + vb * WW * 4 + i];
    __syncthreads();
    const float* vsrc = values + (size_t)plane * HW;
    float* sout = (c0 == CC - 1) ? (out + (size_t)NPLANE + (size_t)plane * HW) : nullptr;
    #pragma unroll
    for (int j = 0; j < ELEMS; ++j) {
      int idx = base + tid + 256 * j;
      float2 m2 = mh2[hh_[j]];
      float2 n2 = nw2[ww_[j]];
      float4 r4 = R4[hh_[j]];
      float4 c4 = C4[ww_[j]];
      // t0=(h_row,w_row) t1=(h_row,w_col) t2=(h_col,w_row) t3=(h_col,w_col)
      float sc = __expf(m2.x * n2.x) * (r4.x + c4.x) * im[0]
               + __expf(m2.x * n2.y) * (r4.y + c4.y) * im[1]
               + __expf(m2.y * n2.x) * (r4.z + c4.z) * im[2]
               + __expf(m2.y * n2.y) * (r4.w + c4.w) * im[3];
      smaxl = fmaxf(smaxl, sc);
      U[j] += sc * vsrc[idx];
      if (sout) sout[idx] = sc;
    }
  }
  float* zout = out + (size_t)(b * CC + c0) * HW;
  #pragma unroll
  for (int j = 0; j < ELEMS; ++j) zout[base + tid + 256 * j] = U[j];
  smaxl = blkmax4(smaxl);
  if (tid == 0)
    atomicMax(reinterpret_cast<unsigned int*>(ws + SMX_OFF + c0), __float_as_uint(smaxl));
}

// ---------------- K5: scale by 1/smax ----------------
__global__ __launch_bounds__(256) void k5_final(float* __restrict__ out,
                                                const float* __restrict__ ws) {
  int total = 2 * NPLANE;
  float ism_last = 1.0f / ws[SMX_OFF + CC - 1];
  for (int i = blockIdx.x * blockDim.x + threadIdx.x; i < total; i += gridDim.x * blockDim.x) {
    float s;
    if (i < NPLANE) {
      int c0 = (i / HW) & (CC - 1);    // (b*CC + c0) & 31 == c0
      s = 1.0f / ws[SMX_OFF + c0];
    } else {
      s = ism_last;
    }
    out[i] *= s;
  }
}

extern "C" void kernel_launch(void* const* d_in, const int* in_sizes, int n_in,
                              void* d_out, int out_size, void* d_ws, size_t ws_size,
                              hipStream_t stream) {
  const float* q = (const float*)d_in[0];
  const float* k = (const float*)d_in[1];
  const float* v = (const float*)d_in[2];
  float* out = (float*)d_out;
  float* ws = (float*)d_ws;
  // zero only the atomic-max slots (rcmax[32][4] + smax[32])
  hipMemsetAsync((char*)d_ws + (size_t)MX_OFF * 4, 0, (size_t)(CC * 4 + CC) * 4, stream);
  k1_plane_sums<<<2 * BC, 256, 0, stream>>>(q, k, ws);
  k2_vec_norm<<<CC * 4, 256, 0, stream>>>(ws);
  k3_rc<<<CC * BC, 256, 0, stream>>>(ws);
  k4_score<<<CC * BB * TILES, 256, 0, stream>>>(v, ws, out);
  k5_final<<<2048, 256, 0, stream>>>(out, ws);
}

// Round 2
// 218.950 us; speedup vs baseline: 1.0655x; 1.0655x over previous
//
#include <hip/hip_runtime.h>
#include <float.h>

#define BB 2
#define CC 32
#define HH 96
#define WW 128
#define HW (HH*WW)           // 12288
#define BC (BB*CC)           // 64
#define NPLANE (BC*HW)       // 786432
#define EPSF 1e-6f

// ---- workspace layout (float offsets) ----
#define QR_OFF 0                               // [B*C][H] query row sums
#define QC_OFF (QR_OFF + BC*HH)                // [B*C][W] query col sums
#define QS_OFF (QC_OFF + BC*WW)                // [B*C]    query totals
#define KR_OFF (QS_OFF + BC)                   // [B*C][H] key row sums
#define KC_OFF (KR_OFF + BC*HH)                // [B*C][W] key col sums
#define KS_OFF (KC_OFF + BC*WW)                // [B*C]    key totals
#define HR_OFF (KS_OFF + BC)                   // [C0][B*C][H] h_row (normed)
#define HC_OFF (HR_OFF + CC*BC*HH)             // [C0][B*C][H] h_col
#define WR_OFF (HC_OFF + CC*BC*HH)             // [C0][B*C][W] w_row
#define WC_OFF (WR_OFF + CC*BC*WW)             // [C0][B*C][W] w_col
#define RV_OFF (WC_OFF + CC*BC*WW)             // [C0][B*C][H][4] 1/R per term
#define CV_OFF (RV_OFF + CC*BC*HH*4)           // [C0][B*C][W][4] 1/C per term
#define MX_OFF (CV_OFF + CC*BC*WW*4)           // [C0][4] rcmax (atomicMax bits)
#define SMX_OFF (MX_OFF + CC*4)                // [C0]    smax

__device__ __forceinline__ float rcpf(float x) { return __builtin_amdgcn_rcpf(x); }

// block-wide max, 256 threads = 4 waves of 64
__device__ __forceinline__ float blkmax4(float v) {
  __shared__ float sred[4];
  #pragma unroll
  for (int o = 32; o > 0; o >>= 1) v = fmaxf(v, __shfl_xor(v, o, 64));
  if ((threadIdx.x & 63) == 0) sred[threadIdx.x >> 6] = v;
  __syncthreads();
  float r = fmaxf(fmaxf(sred[0], sred[1]), fmaxf(sred[2], sred[3]));
  __syncthreads();
  return r;
}

// ---------------- K1: per-plane row/col/total sums (queries and keys) ----------------
__global__ __launch_bounds__(256) void k1_plane_sums(const float* __restrict__ q,
                                                     const float* __restrict__ k,
                                                     float* __restrict__ ws) {
  int pb = blockIdx.x;                 // [0, 2*BC): first BC = queries, rest = keys
  int plane = pb & (BC - 1);
  const float* src = (pb < BC ? q : k) + (size_t)plane * HW;
  float* rowO = ws + (pb < BC ? QR_OFF : KR_OFF) + plane * HH;
  float* colO = ws + (pb < BC ? QC_OFF : KC_OFF) + plane * WW;
  float* totO = ws + (pb < BC ? QS_OFF : KS_OFF) + plane;
  __shared__ float cp[4 * WW];
  __shared__ float rsh[HH];
  __shared__ float wtot[2];
  int tid = threadIdx.x;
  int u = tid >> 6, l = tid & 63;
  float csum0 = 0.f, csum1 = 0.f;
  #pragma unroll 4
  for (int r = 0; r < 24; ++r) {
    int h = u * 24 + r;
    float v0 = src[h * WW + l];
    float v1 = src[h * WW + l + 64];
    csum0 += v0; csum1 += v1;
    float rs = v0 + v1;
    #pragma unroll
    for (int o = 1; o < 64; o <<= 1) rs += __shfl_xor(rs, o, 64);
    if (l == 0) { rowO[h] = rs; rsh[h] = rs; }
  }
  cp[u * WW + l] = csum0;
  cp[u * WW + l + 64] = csum1;
  __syncthreads();
  if (tid < WW) colO[tid] = cp[tid] + cp[WW + tid] + cp[2 * WW + tid] + cp[3 * WW + tid];
  float tv = (tid < HH) ? rsh[tid] : 0.f;
  if (tid < 128) {
    #pragma unroll
    for (int o = 1; o < 64; o <<= 1) tv += __shfl_xor(tv, o, 64);
    if ((tid & 63) == 0) wtot[tid >> 6] = tv;
  }
  __syncthreads();
  if (tid == 0) *totO = wtot[0] + wtot[1];
}

// ---------------- K2: min-max-normalized vectors per (c0, type) ----------------
__device__ __forceinline__ float k2_raw(const float* __restrict__ ws, int type, int c0, int i, int L) {
  int bc = i / L, x = i - bc * L;
  int b = bc >> 5;                     // CC == 32
  if (type == 0) return ws[QS_OFF + b * CC + c0] * ws[KR_OFF + bc * HH + x] + HH * EPSF;
  if (type == 1) return ws[QR_OFF + (b * CC + c0) * HH + x] * ws[KS_OFF + bc] + HH * EPSF;
  if (type == 2) return ws[QS_OFF + b * CC + c0] * ws[KC_OFF + bc * WW + x] + WW * EPSF;
  return ws[QC_OFF + (b * CC + c0) * WW + x] * ws[KS_OFF + bc] + WW * EPSF;
}

__global__ __launch_bounds__(256) void k2_vec_norm(float* __restrict__ ws) {
  int c0 = blockIdx.x >> 2, type = blockIdx.x & 3;
  int L = (type < 2) ? HH : WW;
  int N = BC * L;
  int tid = threadIdx.x;
  float mx = -FLT_MAX, mn = FLT_MAX;
  for (int i = tid; i < N; i += 256) {
    float v = k2_raw(ws, type, c0, i, L);
    mx = fmaxf(mx, v); mn = fminf(mn, v);
  }
  mx = blkmax4(mx);
  mn = -blkmax4(-mn);
  float scale = rcpf(mx - mn);
  int dst = (type == 0 ? HR_OFF : type == 1 ? HC_OFF : type == 2 ? WR_OFF : WC_OFF) + c0 * N;
  for (int i = tid; i < N; i += 256) {
    float v = k2_raw(ws, type, c0, i, L);
    ws[dst + i] = 2.0f + (v - mn) * scale;
  }
}

// ---------------- K3: per (c0,plane): wave u owns term u. No e-matrix in LDS. ----------------
// t0=(h_row,w_row) t1=(h_row,w_col) t2=(h_col,w_row) t3=(h_col,w_col)
__global__ __launch_bounds__(256) void k3_rc(float* __restrict__ ws) {
  int vb = blockIdx.x;                 // c0*BC + plane
  int c0 = vb >> 6;                    // BC == 64
  int tid = threadIdx.x;
  int t = tid >> 6, l = tid & 63;
  __shared__ float mr[HH], mc[HH], nr[WW], nc[WW];
  __shared__ float rRsh[4][HH];
  // stage the 4 normed vectors (2 m-vectors shared by 2 terms each, same for n)
  if (tid < HH) { mr[tid] = ws[HR_OFF + vb * HH + tid]; mc[tid] = ws[HC_OFF + vb * HH + tid]; }
  if (tid < WW) { nr[tid] = ws[WR_OFF + vb * WW + tid]; nc[tid] = ws[WC_OFF + vb * WW + tid]; }
  __syncthreads();
  const float* mv = (t < 2) ? mr : mc;
  const float* nv = ((t & 1) == 0) ? nr : nc;
  float n0 = nv[l], n1 = nv[l + 64];
  float csum0 = 0.f, csum1 = 0.f;
  // pass 1: row sums (butterfly) + column partials in registers
  #pragma unroll 4
  for (int h = 0; h < HH; ++h) {
    float mh = mv[h];
    float e0 = __expf(mh * n0);
    float e1 = __expf(mh * n1);
    csum0 += e0; csum1 += e1;
    float rs = e0 + e1;
    #pragma unroll
    for (int o = 1; o < 64; o <<= 1) rs += __shfl_xor(rs, o, 64);
    float rr = rcpf(rs);
    if (l == 0) { rRsh[t][h] = rr; ws[RV_OFF + (vb * HH + h) * 4 + t] = rr; }
  }
  float rc0 = rcpf(csum0), rc1 = rcpf(csum1);
  ws[CV_OFF + (vb * WW + l) * 4 + t] = rc0;
  ws[CV_OFF + (vb * WW + l + 64) * 4 + t] = rc1;
  // pass 2: rcmax (recompute exp; all wave-local, no barrier needed)
  float mx = 0.f;
  #pragma unroll 4
  for (int h = 0; h < HH; ++h) {
    float mh = mv[h];
    float rr = rRsh[t][h];
    float e0 = __expf(mh * n0);
    float e1 = __expf(mh * n1);
    mx = fmaxf(mx, fmaxf(e0 * (rr + rc0), e1 * (rr + rc1)));
  }
  #pragma unroll
  for (int o = 1; o < 64; o <<= 1) mx = fmaxf(mx, __shfl_xor(mx, o, 64));
  if (l == 0)
    atomicMax(reinterpret_cast<unsigned int*>(ws + MX_OFF + c0 * 4 + t), __float_as_uint(mx));
}

// ---------------- K4: per (c0,b,tile): score, smax, z. TILES=24 for occupancy. ----------------
#define ELEMS 2
#define TILES 24                       // 256*ELEMS*TILES == HW
__global__ __launch_bounds__(256) void k4_score(const float* __restrict__ values,
                                                float* __restrict__ ws,
                                                float* __restrict__ out) {
  int bx = blockIdx.x;                 // (c0*BB + b)*TILES + tile
  int tile = bx % TILES;
  int cb = bx / TILES;
  int b = cb & 1, c0 = cb >> 1;
  int tid = threadIdx.x;
  int base = tile * (256 * ELEMS);     // 512 elems = 4 rows per block
  int w = tid & 127;
  int h0 = tile * 4 + (tid >> 7);      // j=0,1 -> rows h0, h0+2
  __shared__ float mhr[HH], mhc[HH];
  __shared__ float nwr[WW], nwc[WW];
  __shared__ float4 R4[HH];
  __shared__ float4 C4[WW];
  // per-thread im selector: staged flat arrays have t = index&3 = tid&3
  float im_sel = rcpf(ws[MX_OFF + c0 * 4 + (tid & 3)]);
  float U0 = 0.f, U1 = 0.f;
  float smaxl = 0.f;
  for (int c = 0; c < CC; ++c) {
    int plane = b * CC + c;
    int vb = c0 * BC + plane;
    __syncthreads();                   // protect LDS from previous iteration readers
    if (tid < HH) { mhr[tid] = ws[HR_OFF + vb * HH + tid]; mhc[tid] = ws[HC_OFF + vb * HH + tid]; }
    if (tid < WW) { nwr[tid] = ws[WR_OFF + vb * WW + tid]; nwc[tid] = ws[WC_OFF + vb * WW + tid]; }
    {
      float* Rf = reinterpret_cast<float*>(R4);
      float* Cf = reinterpret_cast<float*>(C4);
      #pragma unroll
      for (int i = tid; i < HH * 4; i += 256) Rf[i] = ws[RV_OFF + vb * HH * 4 + i] * im_sel;
      #pragma unroll
      for (int i = tid; i < WW * 4; i += 256) Cf[i] = ws[CV_OFF + vb * WW * 4 + i] * im_sel;
    }
    __syncthreads();
    float n2r = nwr[w], n2c = nwc[w];
    float4 c4 = C4[w];
    const float* vsrc = values + (size_t)plane * HW;
    float* sout = (c0 == CC - 1) ? (out + (size_t)NPLANE + (size_t)plane * HW) : nullptr;
    #pragma unroll
    for (int j = 0; j < ELEMS; ++j) {
      int idx = base + tid + 256 * j;
      int h = h0 + 2 * j;
      float m_r = mhr[h], m_c = mhc[h];
      float4 r4 = R4[h];
      float sc = __expf(m_r * n2r) * (r4.x + c4.x)
               + __expf(m_r * n2c) * (r4.y + c4.y)
               + __expf(m_c * n2r) * (r4.z + c4.z)
               + __expf(m_c * n2c) * (r4.w + c4.w);
      smaxl = fmaxf(smaxl, sc);
      float uv = sc * vsrc[idx];
      if (j == 0) U0 += uv; else U1 += uv;
      if (sout) sout[idx] = sc;
    }
  }
  float* zout = out + (size_t)(b * CC + c0) * HW;
  zout[base + tid] = U0;
  zout[base + tid + 256] = U1;
  smaxl = blkmax4(smaxl);
  if (tid == 0)
    atomicMax(reinterpret_cast<unsigned int*>(ws + SMX_OFF + c0), __float_as_uint(smaxl));
}

// ---------------- K5: scale by 1/smax ----------------
__global__ __launch_bounds__(256) void k5_final(float* __restrict__ out,
                                                const float* __restrict__ ws) {
  int total = 2 * NPLANE;
  float ism_last = rcpf(ws[SMX_OFF + CC - 1]);
  for (int i = blockIdx.x * blockDim.x + threadIdx.x; i < total; i += gridDim.x * blockDim.x) {
    float s;
    if (i < NPLANE) {
      int c0 = (i / HW) & (CC - 1);    // (b*CC + c0) & 31 == c0
      s = rcpf(ws[SMX_OFF + c0]);
    } else {
      s = ism_last;
    }
    out[i] *= s;
  }
}

extern "C" void kernel_launch(void* const* d_in, const int* in_sizes, int n_in,
                              void* d_out, int out_size, void* d_ws, size_t ws_size,
                              hipStream_t stream) {
  const float* q = (const float*)d_in[0];
  const float* k = (const float*)d_in[1];
  const float* v = (const float*)d_in[2];
  float* out = (float*)d_out;
  float* ws = (float*)d_ws;
  // zero only the atomic-max slots (rcmax[32][4] + smax[32])
  hipMemsetAsync((char*)d_ws + (size_t)MX_OFF * 4, 0, (size_t)(CC * 4 + CC) * 4, stream);
  k1_plane_sums<<<2 * BC, 256, 0, stream>>>(q, k, ws);
  k2_vec_norm<<<CC * 4, 256, 0, stream>>>(ws);
  k3_rc<<<CC * BC, 256, 0, stream>>>(ws);
  k4_score<<<CC * BB * TILES, 256, 0, stream>>>(v, ws, out);
  k5_final<<<2048, 256, 0, stream>>>(out, ws);
}

// Round 3
// 173.983 us; speedup vs baseline: 1.3408x; 1.2585x over previous
//
#include <hip/hip_runtime.h>
#include <float.h>

#define BB 2
#define CC 32
#define HH 96
#define WW 128
#define HW (HH*WW)           // 12288
#define BC (BB*CC)           // 64
#define NPLANE (BC*HW)       // 786432
#define EPSF 1e-6f

// ---- workspace layout (float offsets) ----
// base sums (written by K1):
#define QR_OFF 0                               // [B*C][H] query row sums
#define QC_OFF (QR_OFF + BC*HH)                // [B*C][W] query col sums
#define QS_OFF (QC_OFF + BC*WW)                // [B*C]    query totals
#define KR_OFF (QS_OFF + BC)                   // [B*C][H] key row sums
#define KC_OFF (KR_OFF + BC*HH)                // [B*C][W] key col sums
#define KS_OFF (KC_OFF + BC*WW)                // [B*C]    key totals
// per-(c0,plane) packed record (vb = c0*BC + plane), RECSZ floats:
//   [0:96)    m_r  (h_row normed)   -- K2 type 0
//   [96:192)  m_c  (h_col normed)   -- K2 type 1
//   [192:320) n_r  (w_row normed)   -- K2 type 2
//   [320:448) n_c  (w_col normed)   -- K2 type 3
//   [448:832) R4   [h][4] 1/rowsum per term   -- K3
//   [832:1344) C4  [w][4] 1/colsum per term   -- K3
#define REC_OFF (KS_OFF + BC)                  // == 28800
#define RECSZ 1344
#define REC4 (RECSZ/4)                         // 336 float4 per record
#define MX_OFF (REC_OFF + CC*BC*RECSZ)         // [C0][4] rcmax (atomicMax bits)
#define SMX_OFF (MX_OFF + CC*4)                // [C0]    smax
// total = SMX_OFF + CC = 2781472 floats = 11.13 MB (same as validated run)

__device__ __forceinline__ float rcpf(float x) { return __builtin_amdgcn_rcpf(x); }

// block-wide max, 256 threads = 4 waves of 64
__device__ __forceinline__ float blkmax4(float v) {
  __shared__ float sred[4];
  #pragma unroll
  for (int o = 32; o > 0; o >>= 1) v = fmaxf(v, __shfl_xor(v, o, 64));
  if ((threadIdx.x & 63) == 0) sred[threadIdx.x >> 6] = v;
  __syncthreads();
  float r = fmaxf(fmaxf(sred[0], sred[1]), fmaxf(sred[2], sred[3]));
  __syncthreads();
  return r;
}

// ---------------- K1: per-plane row/col/total sums (queries and keys) ----------------
__global__ __launch_bounds__(256) void k1_plane_sums(const float* __restrict__ q,
                                                     const float* __restrict__ k,
                                                     float* __restrict__ ws) {
  int pb = blockIdx.x;                 // [0, 2*BC): first BC = queries, rest = keys
  int plane = pb & (BC - 1);
  const float* src = (pb < BC ? q : k) + (size_t)plane * HW;
  float* rowO = ws + (pb < BC ? QR_OFF : KR_OFF) + plane * HH;
  float* colO = ws + (pb < BC ? QC_OFF : KC_OFF) + plane * WW;
  float* totO = ws + (pb < BC ? QS_OFF : KS_OFF) + plane;
  __shared__ float cp[4 * WW];
  __shared__ float rsh[HH];
  __shared__ float wtot[2];
  int tid = threadIdx.x;
  int u = tid >> 6, l = tid & 63;
  float csum0 = 0.f, csum1 = 0.f;
  #pragma unroll 4
  for (int r = 0; r < 24; ++r) {
    int h = u * 24 + r;
    float v0 = src[h * WW + l];
    float v1 = src[h * WW + l + 64];
    csum0 += v0; csum1 += v1;
    float rs = v0 + v1;
    #pragma unroll
    for (int o = 1; o < 64; o <<= 1) rs += __shfl_xor(rs, o, 64);
    if (l == 0) { rowO[h] = rs; rsh[h] = rs; }
  }
  cp[u * WW + l] = csum0;
  cp[u * WW + l + 64] = csum1;
  __syncthreads();
  if (tid < WW) colO[tid] = cp[tid] + cp[WW + tid] + cp[2 * WW + tid] + cp[3 * WW + tid];
  float tv = (tid < HH) ? rsh[tid] : 0.f;
  if (tid < 128) {
    #pragma unroll
    for (int o = 1; o < 64; o <<= 1) tv += __shfl_xor(tv, o, 64);
    if ((tid & 63) == 0) wtot[tid >> 6] = tv;
  }
  __syncthreads();
  if (tid == 0) *totO = wtot[0] + wtot[1];
}

// ---------------- K2: min-max-normalized vectors, written into records ----------------
__device__ __forceinline__ float k2_raw(const float* __restrict__ ws, int type, int c0, int i, int L) {
  int bc = i / L, x = i - bc * L;
  int b = bc >> 5;                     // CC == 32
  if (type == 0) return ws[QS_OFF + b * CC + c0] * ws[KR_OFF + bc * HH + x] + HH * EPSF;
  if (type == 1) return ws[QR_OFF + (b * CC + c0) * HH + x] * ws[KS_OFF + bc] + HH * EPSF;
  if (type == 2) return ws[QS_OFF + b * CC + c0] * ws[KC_OFF + bc * WW + x] + WW * EPSF;
  return ws[QC_OFF + (b * CC + c0) * WW + x] * ws[KS_OFF + bc] + WW * EPSF;
}

__global__ __launch_bounds__(256) void k2_vec_norm(float* __restrict__ ws) {
  int c0 = blockIdx.x >> 2, type = blockIdx.x & 3;
  int L = (type < 2) ? HH : WW;
  int N = BC * L;
  int field = (type == 0) ? 0 : (type == 1) ? 96 : (type == 2) ? 192 : 320;
  int tid = threadIdx.x;
  float mx = -FLT_MAX, mn = FLT_MAX;
  for (int i = tid; i < N; i += 256) {
    float v = k2_raw(ws, type, c0, i, L);
    mx = fmaxf(mx, v); mn = fminf(mn, v);
  }
  mx = blkmax4(mx);
  mn = -blkmax4(-mn);
  float scale = rcpf(mx - mn);
  for (int i = tid; i < N; i += 256) {
    int bc = i / L, x = i - bc * L;
    float v = k2_raw(ws, type, c0, i, L);
    ws[REC_OFF + (size_t)(c0 * BC + bc) * RECSZ + field + x] = 2.0f + (v - mn) * scale;
  }
}

// ---------------- K3: per (c0,plane): wave t owns term t. No shuffles in hot loops. ----------------
// t0=(m_r,n_r) t1=(m_r,n_c) t2=(m_c,n_r) t3=(m_c,n_c)
__global__ __launch_bounds__(256) void k3_rc(float* __restrict__ ws) {
  int vb = blockIdx.x;                 // c0*BC + plane
  int c0 = vb >> 6;                    // BC == 64
  float* rec = ws + REC_OFF + (size_t)vb * RECSZ;
  int tid = threadIdx.x;
  int t = tid >> 6, l = tid & 63;
  __shared__ __align__(16) float mr[HH], mc[HH], nr[WW], nc[WW];
  __shared__ __align__(16) float R4s[HH][4];
  __shared__ __align__(16) float C4s[WW][4];
  if (tid < HH) { mr[tid] = rec[tid]; mc[tid] = rec[96 + tid]; }
  if (tid < WW) { nr[tid] = rec[192 + tid]; nc[tid] = rec[320 + tid]; }
  __syncthreads();
  const float* mv = (t < 2) ? mr : mc;
  const float* nv = ((t & 1) == 0) ? nr : nc;
  // ---- phase 1: column sums (lane owns cols l, l+64), 4 accumulators ----
  float n0 = nv[l], n1 = nv[l + 64];
  float a0 = 0.f, a1 = 0.f, b0 = 0.f, b1 = 0.f;
  #pragma unroll 8
  for (int h = 0; h < HH; h += 2) {
    float2 m2 = *(const float2*)&mv[h];
    a0 += __expf(m2.x * n0); b0 += __expf(m2.x * n1);
    a1 += __expf(m2.y * n0); b1 += __expf(m2.y * n1);
  }
  float rc0 = rcpf(a0 + a1), rc1 = rcpf(b0 + b1);
  C4s[l][t] = rc0; C4s[l + 64][t] = rc1;
  // ---- phase 2: row sums via 192 half-rows (3 balanced tasks/lane, partner l^1) ----
  int hf = l & 1;                      // which half of w this lane sums
  int hb = l >> 1;                     // row sub-index
  float mh0 = mv[hb], mh1 = mv[32 + hb], mh2 = mv[64 + hb];
  float s0a = 0.f, s1a = 0.f, s2a = 0.f, s0b = 0.f, s1b = 0.f, s2b = 0.f;
  #pragma unroll 8
  for (int j = 0; j < 64; j += 2) {
    float2 x0 = *(const float2*)&nv[j];
    float2 x1 = *(const float2*)&nv[64 + j];
    float p = hf ? x1.x : x0.x;
    float q = hf ? x1.y : x0.y;
    s0a += __expf(mh0 * p); s0b += __expf(mh0 * q);
    s1a += __expf(mh1 * p); s1b += __expf(mh1 * q);
    s2a += __expf(mh2 * p); s2b += __expf(mh2 * q);
  }
  float r0 = s0a + s0b; r0 += __shfl_xor(r0, 1, 64);
  float r1 = s1a + s1b; r1 += __shfl_xor(r1, 1, 64);
  float r2 = s2a + s2b; r2 += __shfl_xor(r2, 1, 64);
  if (hf == 0) {
    R4s[hb][t] = rcpf(r0);
    R4s[32 + hb][t] = rcpf(r1);
    R4s[64 + hb][t] = rcpf(r2);
  }
  // ---- phase 3: rcmax (lane owns cols again; recompute exp; wave-local) ----
  float mx = 0.f;
  #pragma unroll 4
  for (int h = 0; h < HH; h += 2) {
    float2 m2 = *(const float2*)&mv[h];
    float rr0 = R4s[h][t], rr1 = R4s[h + 1][t];
    mx = fmaxf(mx, fmaxf(__expf(m2.x * n0) * (rr0 + rc0), __expf(m2.x * n1) * (rr0 + rc1)));
    mx = fmaxf(mx, fmaxf(__expf(m2.y * n0) * (rr1 + rc0), __expf(m2.y * n1) * (rr1 + rc1)));
  }
  #pragma unroll
  for (int o = 1; o < 64; o <<= 1) mx = fmaxf(mx, __shfl_xor(mx, o, 64));
  if (l == 0)
    atomicMax(reinterpret_cast<unsigned int*>(ws + MX_OFF + c0 * 4 + t), __float_as_uint(mx));
  // ---- cooperative coalesced copy of R4s/C4s into the record ----
  __syncthreads();
  const float* Rf = &R4s[0][0];
  const float* Cf = &C4s[0][0];
  for (int i = tid; i < HH * 4; i += 256) rec[448 + i] = Rf[i];
  for (int i = tid; i < WW * 4; i += 256) rec[832 + i] = Cf[i];
}

// ---------------- K4: direct-load score/z/smax. No LDS staging, no barriers. ----------------
#define ELEMS 4
#define TILES 12                       // 256*ELEMS*TILES == HW
__global__ __launch_bounds__(256) void k4_score(const float* __restrict__ values,
                                                float* __restrict__ ws,
                                                float* __restrict__ out) {
  int bx = blockIdx.x;                 // (c0*BB + b)*TILES + tile
  int tile = bx % TILES;
  int cb = bx / TILES;
  int b = cb & 1, c0 = cb >> 1;
  int tid = threadIdx.x;
  int base = tile * (256 * ELEMS);     // 1024 elems = 8 rows per block
  int w = tid & 127;
  int h0 = tile * 8 + (tid >> 7);      // j -> rows h0 + 2j
  float im0 = rcpf(ws[MX_OFF + c0 * 4 + 0]);
  float im1 = rcpf(ws[MX_OFF + c0 * 4 + 1]);
  float im2 = rcpf(ws[MX_OFF + c0 * 4 + 2]);
  float im3 = rcpf(ws[MX_OFF + c0 * 4 + 3]);
  const float* rec0 = ws + REC_OFF + (size_t)(c0 * BC + b * CC) * RECSZ;
  const float* vsrc0 = values + (size_t)(b * CC) * HW + base + tid;
  float* sbase = out + (size_t)NPLANE + (size_t)(b * CC) * HW + base + tid;
  bool writeS = (c0 == CC - 1);
  float U[ELEMS] = {0.f, 0.f, 0.f, 0.f};
  float smaxl = 0.f;
  for (int c = 0; c < CC; ++c) {
    const float* rec = rec0 + (size_t)c * RECSZ;
    const float* vsrc = vsrc0 + (size_t)c * HW;
    float n2r = rec[192 + w], n2c = rec[320 + w];
    float4 c4 = *(const float4*)(rec + 832 + 4 * w);
    float A0 = c4.x * im0, A1 = c4.y * im1, A2 = c4.z * im2, A3 = c4.w * im3;
    #pragma unroll
    for (int j = 0; j < ELEMS; ++j) {
      int h = h0 + 2 * j;
      float m_r = rec[h], m_c = rec[96 + h];
      float4 r4 = *(const float4*)(rec + 448 + 4 * h);
      float sc = __expf(m_r * n2r) * (r4.x * im0 + A0)
               + __expf(m_r * n2c) * (r4.y * im1 + A1)
               + __expf(m_c * n2r) * (r4.z * im2 + A2)
               + __expf(m_c * n2c) * (r4.w * im3 + A3);
      smaxl = fmaxf(smaxl, sc);
      U[j] += sc * vsrc[256 * j];
      if (writeS) sbase[(size_t)c * HW + 256 * j] = sc;
    }
  }
  float* zout = out + (size_t)(b * CC + c0) * HW + base + tid;
  #pragma unroll
  for (int j = 0; j < ELEMS; ++j) zout[256 * j] = U[j];
  smaxl = blkmax4(smaxl);
  if (tid == 0)
    atomicMax(reinterpret_cast<unsigned int*>(ws + SMX_OFF + c0), __float_as_uint(smaxl));
}

// ---------------- K5: scale by 1/smax ----------------
__global__ __launch_bounds__(256) void k5_final(float* __restrict__ out,
                                                const float* __restrict__ ws) {
  int total = 2 * NPLANE;
  float ism_last = rcpf(ws[SMX_OFF + CC - 1]);
  for (int i = blockIdx.x * blockDim.x + threadIdx.x; i < total; i += gridDim.x * blockDim.x) {
    float s;
    if (i < NPLANE) {
      int c0 = (i / HW) & (CC - 1);    // (b*CC + c0) & 31 == c0
      s = rcpf(ws[SMX_OFF + c0]);
    } else {
      s = ism_last;
    }
    out[i] *= s;
  }
}

extern "C" void kernel_launch(void* const* d_in, const int* in_sizes, int n_in,
                              void* d_out, int out_size, void* d_ws, size_t ws_size,
                              hipStream_t stream) {
  const float* q = (const float*)d_in[0];
  const float* k = (const float*)d_in[1];
  const float* v = (const float*)d_in[2];
  float* out = (float*)d_out;
  float* ws = (float*)d_ws;
  // zero only the atomic-max slots (rcmax[32][4] + smax[32])
  hipMemsetAsync((char*)d_ws + (size_t)MX_OFF * 4, 0, (size_t)(CC * 4 + CC) * 4, stream);
  k1_plane_sums<<<2 * BC, 256, 0, stream>>>(q, k, ws);
  k2_vec_norm<<<CC * 4, 256, 0, stream>>>(ws);
  k3_rc<<<CC * BC, 256, 0, stream>>>(ws);
  k4_score<<<CC * BB * TILES, 256, 0, stream>>>(v, ws, out);
  k5_final<<<2048, 256, 0, stream>>>(out, ws);
}

// Round 4
// 141.139 us; speedup vs baseline: 1.6529x; 1.2327x over previous
//
#include <hip/hip_runtime.h>
#include <hip/hip_fp16.h>
#include <float.h>

#define BB 2
#define CC 32
#define HH 96
#define WW 128
#define HW (HH*WW)           // 12288
#define BC (BB*CC)           // 64
#define NPLANE (BC*HW)       // 786432
#define EPSF 1e-6f
#define LOG2E 1.4426950408889634f

// ---- workspace layout (float offsets) ----
#define QR_OFF 0                               // [B*C][H] query row sums
#define QC_OFF (QR_OFF + BC*HH)                // [B*C][W] query col sums
#define QS_OFF (QC_OFF + BC*WW)                // [B*C]    query totals
#define KR_OFF (QS_OFF + BC)                   // [B*C][H] key row sums
#define KC_OFF (KR_OFF + BC*HH)                // [B*C][W] key col sums
#define KS_OFF (KC_OFF + BC*WW)                // [B*C]    key totals
// per-(c0,plane) packed record (vb = c0*BC + plane), RECSZ floats:
//   [0:192)    m pairs   [h][2] = (m_r, m_c), PRE-MULTIPLIED by log2e
//   [192:448)  n pairs   [w][2] = (n_r, n_c)
//   [448:832)  R4        [h][4] 1/rowsum per term
//   [832:1344) C4        [w][4] 1/colsum per term
#define REC_OFF (KS_OFF + BC)                  // == 28800
#define RECSZ 1344
#define MX_OFF (REC_OFF + CC*BC*RECSZ)         // [C0][4] rcmax (atomicMax bits)
#define SMX_OFF (MX_OFF + CC*4)                // [C0]    smax
// total = SMX_OFF + CC = 2781472 floats = 11.13 MB (same as validated runs)

__device__ __forceinline__ float rcpf(float x) { return __builtin_amdgcn_rcpf(x); }
__device__ __forceinline__ float e2(float x) { return __builtin_amdgcn_exp2f(x); }

// block-wide max, 256 threads = 4 waves of 64
__device__ __forceinline__ float blkmax4(float v) {
  __shared__ float sred[4];
  #pragma unroll
  for (int o = 32; o > 0; o >>= 1) v = fmaxf(v, __shfl_xor(v, o, 64));
  if ((threadIdx.x & 63) == 0) sred[threadIdx.x >> 6] = v;
  __syncthreads();
  float r = fmaxf(fmaxf(sred[0], sred[1]), fmaxf(sred[2], sred[3]));
  __syncthreads();
  return r;
}

// ---------------- K1: per-plane row/col/total sums (queries and keys) ----------------
__global__ __launch_bounds__(256) void k1_plane_sums(const float* __restrict__ q,
                                                     const float* __restrict__ k,
                                                     float* __restrict__ ws) {
  int pb = blockIdx.x;                 // [0, 2*BC): first BC = queries, rest = keys
  int plane = pb & (BC - 1);
  const float* src = (pb < BC ? q : k) + (size_t)plane * HW;
  float* rowO = ws + (pb < BC ? QR_OFF : KR_OFF) + plane * HH;
  float* colO = ws + (pb < BC ? QC_OFF : KC_OFF) + plane * WW;
  float* totO = ws + (pb < BC ? QS_OFF : KS_OFF) + plane;
  __shared__ float cp[4 * WW];
  __shared__ float rsh[HH];
  __shared__ float wtot[2];
  int tid = threadIdx.x;
  int u = tid >> 6, l = tid & 63;
  float csum0 = 0.f, csum1 = 0.f;
  #pragma unroll 4
  for (int r = 0; r < 24; ++r) {
    int h = u * 24 + r;
    float v0 = src[h * WW + l];
    float v1 = src[h * WW + l + 64];
    csum0 += v0; csum1 += v1;
    float rs = v0 + v1;
    #pragma unroll
    for (int o = 1; o < 64; o <<= 1) rs += __shfl_xor(rs, o, 64);
    if (l == 0) { rowO[h] = rs; rsh[h] = rs; }
  }
  cp[u * WW + l] = csum0;
  cp[u * WW + l + 64] = csum1;
  __syncthreads();
  if (tid < WW) colO[tid] = cp[tid] + cp[WW + tid] + cp[2 * WW + tid] + cp[3 * WW + tid];
  float tv = (tid < HH) ? rsh[tid] : 0.f;
  if (tid < 128) {
    #pragma unroll
    for (int o = 1; o < 64; o <<= 1) tv += __shfl_xor(tv, o, 64);
    if ((tid & 63) == 0) wtot[tid >> 6] = tv;
  }
  __syncthreads();
  if (tid == 0) *totO = wtot[0] + wtot[1];
}

// ---------------- K2: min-max-normalized vectors into paired record fields ----------------
__device__ __forceinline__ float k2_raw(const float* __restrict__ ws, int type, int c0, int i, int L) {
  int bc = i / L, x = i - bc * L;
  int b = bc >> 5;                     // CC == 32
  if (type == 0) return ws[QS_OFF + b * CC + c0] * ws[KR_OFF + bc * HH + x] + HH * EPSF;
  if (type == 1) return ws[QR_OFF + (b * CC + c0) * HH + x] * ws[KS_OFF + bc] + HH * EPSF;
  if (type == 2) return ws[QS_OFF + b * CC + c0] * ws[KC_OFF + bc * WW + x] + WW * EPSF;
  return ws[QC_OFF + (b * CC + c0) * WW + x] * ws[KS_OFF + bc] + WW * EPSF;
}

__global__ __launch_bounds__(256) void k2_vec_norm(float* __restrict__ ws) {
  int c0 = blockIdx.x >> 2, type = blockIdx.x & 3;
  int L = (type < 2) ? HH : WW;
  int N = BC * L;
  int tid = threadIdx.x;
  float mx = -FLT_MAX, mn = FLT_MAX;
  for (int i = tid; i < N; i += 256) {
    float v = k2_raw(ws, type, c0, i, L);
    mx = fmaxf(mx, v); mn = fminf(mn, v);
  }
  mx = blkmax4(mx);
  mn = -blkmax4(-mn);
  float scale = rcpf(mx - mn);
  float fold = (type < 2) ? LOG2E : 1.0f;      // m-vectors carry the log2e factor
  int fieldbase = (type < 2) ? (type & 1) : (192 + (type & 1));
  for (int i = tid; i < N; i += 256) {
    int bc = i / L, x = i - bc * L;
    float v = k2_raw(ws, type, c0, i, L);
    ws[REC_OFF + (size_t)(c0 * BC + bc) * RECSZ + fieldbase + 2 * x] =
        (2.0f + (v - mn) * scale) * fold;
  }
}

// ---------------- K3: per (c0,plane); 4 waves cooperate per term; e staged fp16 in LDS ----------------
// t0=(m_r,n_r) t1=(m_r,n_c) t2=(m_c,n_r) t3=(m_c,n_c)
#define EPH 136                        // padded halves per row (272B rows, 16B-aligned)
__global__ __launch_bounds__(256) void k3_rc(float* __restrict__ ws) {
  int vb = blockIdx.x;                 // c0*BC + plane
  int c0 = vb >> 6;                    // BC == 64
  float* rec = ws + REC_OFF + (size_t)vb * RECSZ;
  int tid = threadIdx.x;
  __shared__ __align__(16) __half eh[HH * EPH];     // 26112 B
  __shared__ __align__(16) float mbuf[2 * HH];      // (m_r,m_c) pairs (×log2e)
  __shared__ __align__(16) float nbuf[2 * WW];      // (n_r,n_c) pairs
  __shared__ __align__(16) float R4s[HH][4];
  __shared__ __align__(16) float C4s[WW][4];
  __shared__ __align__(16) float rR_lin[HH];
  __shared__ __align__(16) float rC_lin[WW];
  __shared__ __align__(16) float cpart[4][WW];
  if (tid < 192) mbuf[tid] = rec[tid];
  nbuf[tid] = rec[192 + tid];
  __syncthreads();
  int u = tid >> 6;                    // phaseA row group (24 rows)
  int col0 = (tid & 63) * 2;           // phaseA: 2 adjacent columns
  int rB = tid >> 1, hfB = tid & 1;    // phaseB/C: half-rows (tid<192)
  float mx[4];
  #pragma unroll
  for (int t = 0; t < 4; ++t) {
    int msel = t >> 1, nsel = t & 1;
    // ---- phase A: compute e once, col partials in regs, store fp16 ----
    float n0 = nbuf[2 * col0 + nsel];
    float n1 = nbuf[2 * (col0 + 1) + nsel];
    float cs0 = 0.f, cs1 = 0.f;
    #pragma unroll 6
    for (int r = 0; r < 24; ++r) {
      int h = u * 24 + r;
      float mh = mbuf[2 * h + msel];
      float e0 = e2(mh * n0);
      float e1 = e2(mh * n1);
      cs0 += e0; cs1 += e1;
      *reinterpret_cast<__half2*>(&eh[h * EPH + col0]) = __floats2half2_rn(e0, e1);
    }
    cpart[u][col0] = cs0;
    cpart[u][col0 + 1] = cs1;
    __syncthreads();
    // ---- phase B: waves 0-2 row sums from LDS; wave 3 col combine ----
    if (tid < 192) {
      const uint4* p = (const uint4*)&eh[rB * EPH + hfB * 64];
      float s0 = 0.f, s1 = 0.f, s2 = 0.f, s3 = 0.f;
      #pragma unroll
      for (int i = 0; i < 8; ++i) {
        uint4 ev = p[i];
        float2 f0 = __half22float2(*(const __half2*)&ev.x);
        float2 f1 = __half22float2(*(const __half2*)&ev.y);
        float2 f2 = __half22float2(*(const __half2*)&ev.z);
        float2 f3 = __half22float2(*(const __half2*)&ev.w);
        s0 += f0.x + f0.y; s1 += f1.x + f1.y;
        s2 += f2.x + f2.y; s3 += f3.x + f3.y;
      }
      float s = (s0 + s1) + (s2 + s3);
      s += __shfl_xor(s, 1, 64);
      if (hfB == 0) { float rr = rcpf(s); R4s[rB][t] = rr; rR_lin[rB] = rr; }
    } else {
      int wc = tid - 192;
      float rc0 = rcpf(cpart[0][wc] + cpart[1][wc] + cpart[2][wc] + cpart[3][wc]);
      float rc1 = rcpf(cpart[0][wc + 64] + cpart[1][wc + 64] + cpart[2][wc + 64] + cpart[3][wc + 64]);
      C4s[wc][t] = rc0;  C4s[wc + 64][t] = rc1;
      rC_lin[wc] = rc0;  rC_lin[wc + 64] = rc1;
    }
    __syncthreads();
    // ---- phase C: max of e*(rR+rC) from LDS ----
    float ml = 0.f;
    if (tid < 192) {
      float rr = rR_lin[rB];
      const uint4* p = (const uint4*)&eh[rB * EPH + hfB * 64];
      const float4* pc = (const float4*)&rC_lin[hfB * 64];
      #pragma unroll
      for (int i = 0; i < 8; ++i) {
        uint4 ev = p[i];
        float4 ca = pc[2 * i], cb = pc[2 * i + 1];
        float2 f0 = __half22float2(*(const __half2*)&ev.x);
        float2 f1 = __half22float2(*(const __half2*)&ev.y);
        float2 f2 = __half22float2(*(const __half2*)&ev.z);
        float2 f3 = __half22float2(*(const __half2*)&ev.w);
        ml = fmaxf(ml, fmaxf(f0.x * (rr + ca.x), f0.y * (rr + ca.y)));
        ml = fmaxf(ml, fmaxf(f1.x * (rr + ca.z), f1.y * (rr + ca.w)));
        ml = fmaxf(ml, fmaxf(f2.x * (rr + cb.x), f2.y * (rr + cb.y)));
        ml = fmaxf(ml, fmaxf(f3.x * (rr + cb.z), f3.y * (rr + cb.w)));
      }
    }
    mx[t] = ml;
    __syncthreads();                   // eh/cpart reused by next term
  }
  #pragma unroll
  for (int t = 0; t < 4; ++t) {
    float v = blkmax4(mx[t]);
    if (tid == 0)
      atomicMax(reinterpret_cast<unsigned int*>(ws + MX_OFF + c0 * 4 + t), __float_as_uint(v));
  }
  // coalesced write-out of R4/C4 into the record
  const float* Rf = &R4s[0][0];
  const float* Cf = &C4s[0][0];
  for (int i = tid; i < HH * 4; i += 256) rec[448 + i] = Rf[i];
  for (int i = tid; i < WW * 4; i += 256) rec[832 + i] = Cf[i];
}

// ---------------- K4: LDS double-buffered rec staging; score, smax, z ----------------
#define ELEMS 2
#define TILES 24                       // 256*ELEMS*TILES == HW
__global__ __launch_bounds__(256) void k4_score(const float* __restrict__ values,
                                                float* __restrict__ ws,
                                                float* __restrict__ out) {
  int bx = blockIdx.x;                 // (c0*BB + b)*TILES + tile
  int tile = bx % TILES;
  int cb = bx / TILES;
  int b = cb & 1, c0 = cb >> 1;
  int tid = threadIdx.x;
  int base = tile * 512;               // 4 rows per block
  int w = tid & 127;
  int h0 = tile * 4 + (tid >> 7);      // j -> rows h0 + 2j
  __shared__ __align__(16) float buf[2][RECSZ];   // 10752 B
  float im0 = rcpf(ws[MX_OFF + c0 * 4 + 0]);
  float im1 = rcpf(ws[MX_OFF + c0 * 4 + 1]);
  float im2 = rcpf(ws[MX_OFF + c0 * 4 + 2]);
  float im3 = rcpf(ws[MX_OFF + c0 * 4 + 3]);
  const float* rec0 = ws + REC_OFF + (size_t)(c0 * BC + b * CC) * RECSZ;
  bool sec = tid < (RECSZ / 4 - 256);  // 80 tail float4s
  float4 g0 = *(const float4*)(rec0 + 4 * tid);
  float4 g1 = sec ? *(const float4*)(rec0 + 1024 + 4 * tid) : float4{0.f, 0.f, 0.f, 0.f};
  ((float4*)buf[0])[tid] = g0;
  if (sec) ((float4*)buf[0])[256 + tid] = g1;
  float U0 = 0.f, U1 = 0.f, smaxl = 0.f;
  const float* vsrc0 = values + (size_t)(b * CC) * HW + base + tid;
  float* sbase = out + (size_t)NPLANE + (size_t)(b * CC) * HW + base + tid;
  bool writeS = (c0 == CC - 1);
  for (int c = 0; c < CC; ++c) {
    if (c + 1 < CC) {                  // issue next channel's loads early (T14)
      const float* nr = rec0 + (size_t)(c + 1) * RECSZ;
      g0 = *(const float4*)(nr + 4 * tid);
      if (sec) g1 = *(const float4*)(nr + 1024 + 4 * tid);
    }
    __syncthreads();                   // buf[c&1] staged & prior readers done
    const float* B = buf[c & 1];
    float2 n2 = *(const float2*)(B + 192 + 2 * w);
    float4 c4 = *(const float4*)(B + 832 + 4 * w);
    float A0 = c4.x * im0, A1 = c4.y * im1, A2 = c4.z * im2, A3 = c4.w * im3;
    const float* vsrc = vsrc0 + (size_t)c * HW;
    #pragma unroll
    for (int j = 0; j < ELEMS; ++j) {
      int h = h0 + 2 * j;
      float2 m2 = *(const float2*)(B + 2 * h);
      float4 r4 = *(const float4*)(B + 448 + 4 * h);
      float gx = fmaf(r4.x, im0, A0);
      float gy = fmaf(r4.y, im1, A1);
      float gz = fmaf(r4.z, im2, A2);
      float gw = fmaf(r4.w, im3, A3);
      float sc = e2(m2.x * n2.x) * gx + e2(m2.x * n2.y) * gy
               + e2(m2.y * n2.x) * gz + e2(m2.y * n2.y) * gw;
      smaxl = fmaxf(smaxl, sc);
      float uv = sc * vsrc[256 * j];
      if (j == 0) U0 += uv; else U1 += uv;
      if (writeS) sbase[(size_t)c * HW + 256 * j] = sc;
    }
    if (c + 1 < CC) {                  // write-late into the other buffer
      float* Wb = buf[(c + 1) & 1];
      ((float4*)Wb)[tid] = g0;
      if (sec) ((float4*)Wb)[256 + tid] = g1;
    }
  }
  float* zout = out + (size_t)(b * CC + c0) * HW + base + tid;
  zout[0] = U0;
  zout[256] = U1;
  smaxl = blkmax4(smaxl);
  if (tid == 0)
    atomicMax(reinterpret_cast<unsigned int*>(ws + SMX_OFF + c0), __float_as_uint(smaxl));
}

// ---------------- K5: scale by 1/smax ----------------
__global__ __launch_bounds__(256) void k5_final(float* __restrict__ out,
                                                const float* __restrict__ ws) {
  int total = 2 * NPLANE;
  float ism_last = rcpf(ws[SMX_OFF + CC - 1]);
  for (int i = blockIdx.x * blockDim.x + threadIdx.x; i < total; i += gridDim.x * blockDim.x) {
    float s;
    if (i < NPLANE) {
      int c0 = (i / HW) & (CC - 1);    // (b*CC + c0) & 31 == c0
      s = rcpf(ws[SMX_OFF + c0]);
    } else {
      s = ism_last;
    }
    out[i] *= s;
  }
}

extern "C" void kernel_launch(void* const* d_in, const int* in_sizes, int n_in,
                              void* d_out, int out_size, void* d_ws, size_t ws_size,
                              hipStream_t stream) {
  const float* q = (const float*)d_in[0];
  const float* k = (const float*)d_in[1];
  const float* v = (const float*)d_in[2];
  float* out = (float*)d_out;
  float* ws = (float*)d_ws;
  // zero only the atomic-max slots (rcmax[32][4] + smax[32])
  hipMemsetAsync((char*)d_ws + (size_t)MX_OFF * 4, 0, (size_t)(CC * 4 + CC) * 4, stream);
  k1_plane_sums<<<2 * BC, 256, 0, stream>>>(q, k, ws);
  k2_vec_norm<<<CC * 4, 256, 0, stream>>>(ws);
  k3_rc<<<CC * BC, 256, 0, stream>>>(ws);
  k4_score<<<CC * BB * TILES, 256, 0, stream>>>(v, ws, out);
  k5_final<<<2048, 256, 0, stream>>>(out, ws);
}